// Round 1
// baseline (10835.160 us; speedup 1.0000x reference)
//
#include <hip/hip_runtime.h>

typedef __attribute__((ext_vector_type(8))) short short8;
typedef __attribute__((ext_vector_type(4))) float f32x4;
typedef __attribute__((ext_vector_type(4))) int int4v;

#define HD 1024
#define BD 64
#define TD 512
#define BH 65536UL  // one h slot: 64*1024
#define NBLK 194

// ---------------- workspace layout ----------------
#define M4 4194304UL
#define OFF_WHH0 0UL
#define OFF_WIH1 (1UL * M4)
#define OFF_WHH1 (2UL * M4)
#define OFF_WIH2 (3UL * M4)
#define OFF_WHH2 (4UL * M4)
#define OFF_WOUT (5UL * M4)                 // 128 x 1024 (padded rows zeroed)
#define OFF_H0   (OFF_WOUT + 131072UL)      // [4 slots][64][1024] each layer
#define OFF_H1   (OFF_H0 + 262144UL)
#define OFF_H2   (OFF_H1 + 262144UL)
#define USHORT_TOTAL (OFF_H2 + 262144UL)    // 21889024
#define FBYTE_BASE (USHORT_TOTAL * 2UL)
#define FOFF_C0 0UL                          // c stored [j][b] (transposed)
#define FOFF_C1 65536UL
#define FOFF_C2 131072UL
#define FOFF_B0 196608UL                     // combined biases b_ih+b_hh [4096]
#define FOFF_B1 200704UL
#define FOFF_B2 204800UL
#define FOFF_BOUT 208896UL                   // [128], pad zeroed
#define FOFF_FLAGS 209024UL                  // int-indexed: 4 layers x 256 per-wave flags
#define PREP_TOTAL 22099072UL

__device__ __forceinline__ unsigned short f2bf(float f) {
  union { float f; unsigned u; } v; v.f = f;
  unsigned r = v.u + 0x7fffu + ((v.u >> 16) & 1u);  // RNE
  return (unsigned short)(r >> 16);
}
__device__ __forceinline__ float sigmoidf_(float x) {
  return 1.0f / (1.0f + __expf(-x));
}
// LDS bank swizzle: inject gn's high bits into bank bits 0-1 and gn&7 into
// bits 2-4. Writes: ~4-way (was 8-way). Reads (fixed gn, consecutive b):
// b^const is a permutation -> 2-way (free).
__device__ __forceinline__ int sw(int gn, int b) {
  return gn * 64 + (b ^ (((gn & 7) << 2) | ((gn >> 3) & 3)));
}

// Raw agent-coherent (L2-bypass) 16B load. Volatile asm => program-order
// issue among themselves; vmcnt managed explicitly by AWAIT_N.
__device__ __forceinline__ void gload16(int4v& dst, const unsigned short* p) {
  asm volatile("global_load_dwordx4 %0, %1, off sc1" : "=v"(dst) : "v"(p));
}
#define AWAIT_N(N, a0, a1, a2, a3) \
  asm volatile("s_waitcnt vmcnt(" #N ")" : "+v"(a0), "+v"(a1), "+v"(a2), "+v"(a3))

// ---------------- distributed flag "barrier" ----------------
// Per-wave progress flags, one 256-int array per layer (real entries 0 for
// layers 0-2; out-layer has 8 real + 248 entries preset to 2^29 by prep).
// Signal: ONE plain sc1 store per wave (no RMW -> no serialization).
// Wait: ONE dwordx4 per lane covers all 256 flags; min4 + __all ballot.
__device__ __forceinline__ void fload4(int4v& v, const int* p) {
  asm volatile("global_load_dwordx4 %0, %1, off sc1" : "=v"(v) : "v"(p));
  asm volatile("s_waitcnt vmcnt(0)" : "+v"(v));
}
__device__ __forceinline__ bool all_ge(const int4v& v, int k) {
  int a = v[0] < v[1] ? v[0] : v[1];
  int b = v[2] < v[3] ? v[2] : v[3];
  int m = a < b ? a : b;
  return __all(m >= k) != 0;
}
__device__ __forceinline__ void wait_ge(const int* f, int lane, int k) {
  const int* p = f + lane * 4;
  for (;;) {
    int4v v; fload4(v, p);
    if (all_ge(v, k)) return;
    __builtin_amdgcn_s_sleep(1);
  }
}
__device__ __forceinline__ void wait_ge2(const int* fa, int ka, const int* fb, int kb, int lane) {
  const int* pa = fa + lane * 4;
  const int* pb = fb + lane * 4;
  for (;;) {
    int4v va, vb;
    asm volatile("global_load_dwordx4 %0, %1, off sc1" : "=v"(va) : "v"(pa));
    asm volatile("global_load_dwordx4 %0, %1, off sc1" : "=v"(vb) : "v"(pb));
    asm volatile("s_waitcnt vmcnt(0)" : "+v"(va), "+v"(vb));
    if (all_ge(va, ka) && all_ge(vb, kb)) return;
    __builtin_amdgcn_s_sleep(1);
  }
}

// ---------------- prep ----------------
__global__ void prep_kernel(const float* __restrict__ Whh0, const float* __restrict__ Wih1,
                            const float* __restrict__ Whh1, const float* __restrict__ Wih2,
                            const float* __restrict__ Whh2, const float* __restrict__ Wout,
                            const float* __restrict__ bih0, const float* __restrict__ bhh0,
                            const float* __restrict__ bih1, const float* __restrict__ bhh1,
                            const float* __restrict__ bih2, const float* __restrict__ bhh2,
                            const float* __restrict__ bout, void* wsv) {
  unsigned short* u = (unsigned short*)wsv;
  float* fr = (float*)((char*)wsv + FBYTE_BASE);
  int* fi = (int*)fr;
  size_t stride = (size_t)gridDim.x * blockDim.x;
  for (size_t i = (size_t)blockIdx.x * blockDim.x + threadIdx.x; i < PREP_TOTAL; i += stride) {
    if (i < 20971520UL) {
      size_t which = i >> 22;
      size_t off = i & (M4 - 1UL);
      const float* src = (which == 0) ? Whh0 : (which == 1) ? Wih1 :
                         (which == 2) ? Whh1 : (which == 3) ? Wih2 : Whh2;
      u[i] = f2bf(src[off]);
    } else if (i < 21102592UL) {
      size_t k = i - 20971520UL;
      size_t o = k >> 10, kk = k & 1023UL;
      u[i] = (o < 121) ? f2bf(Wout[o * 1024UL + kk]) : (unsigned short)0;
    } else if (i < 21889024UL) {
      u[i] = 0;                                   // zero all 4 h slots x 3 layers
    } else if (i < 22085632UL) {
      fr[i - 21889024UL] = 0.0f;                  // zero c0,c1,c2
    } else if (i < 22097920UL) {
      size_t k = i - 22085632UL;
      size_t l = k >> 12, n = k & 4095UL;
      const float* bi = (l == 0) ? bih0 : (l == 1) ? bih1 : bih2;
      const float* bh = (l == 0) ? bhh0 : (l == 1) ? bhh1 : bhh2;
      fr[FOFF_B0 + l * 4096UL + n] = bi[n] + bh[n];
    } else if (i < 22098048UL) {
      size_t k = i - 22097920UL;
      fr[FOFF_BOUT + k] = (k < 121) ? bout[k] : 0.0f;
    } else {
      size_t k = i - 22098048UL;                  // flags: layers 0-2 full, out 8 real
      fi[FOFF_FLAGS + k] = (k < 776UL) ? 0 : (1 << 29);
    }
  }
}

// ---------------- GEMM slice: register B, 6-deep explicit-vmcnt pipelined A ----------------
template <int NK>
__device__ __forceinline__ void gemm_bw(const unsigned short* __restrict__ arow,
                                        const short8 (&bw)[NK][4],
                                        f32x4 (&acc)[4][4]) {
  static_assert(NK >= 6, "pipeline depth");
  int4v ap[6][4];
#pragma unroll
  for (int g = 0; g < 6; ++g)
#pragma unroll
    for (int mt = 0; mt < 4; ++mt)
      gload16(ap[g][mt], arow + mt * 16 * HD + g * 32);
#pragma unroll
  for (int k = 0; k < NK; ++k) {
    const int s = k % 6;
    if (k <= NK - 6)          { AWAIT_N(20, ap[s][0], ap[s][1], ap[s][2], ap[s][3]); }
    else if (NK - 1 - k == 4) { AWAIT_N(16, ap[s][0], ap[s][1], ap[s][2], ap[s][3]); }
    else if (NK - 1 - k == 3) { AWAIT_N(12, ap[s][0], ap[s][1], ap[s][2], ap[s][3]); }
    else if (NK - 1 - k == 2) { AWAIT_N(8,  ap[s][0], ap[s][1], ap[s][2], ap[s][3]); }
    else if (NK - 1 - k == 1) { AWAIT_N(4,  ap[s][0], ap[s][1], ap[s][2], ap[s][3]); }
    else                      { AWAIT_N(0,  ap[s][0], ap[s][1], ap[s][2], ap[s][3]); }
#pragma unroll
    for (int mt = 0; mt < 4; ++mt) {
      short8 a = *(short8*)&ap[s][mt];
#pragma unroll
      for (int ns = 0; ns < 4; ++ns)
        acc[ns][mt] = __builtin_amdgcn_mfma_f32_16x16x32_bf16(a, bw[k][ns], acc[ns][mt], 0, 0, 0);
    }
    if (k + 6 < NK) {
#pragma unroll
      for (int mt = 0; mt < 4; ++mt)
        gload16(ap[s][mt], arow + mt * 16 * HD + (k + 6) * 32);
    }
  }
}

// ---------------- persistent-weight layer driver (dataflow-synced) ----------------
// RAW: own-layer flags >= t (recurrent all-to-all), producer flags >= t+1.
// WAR: 4-deep h slots; writing h[t] destroys h[t-4] -> consumer flags >= t-3,
// probed non-blockingly before the GEMM (monotonic), re-polled (rare) before store.
template <bool L0L>
__device__ __forceinline__ void run_layer(
    int wgl, int tid,
    const unsigned short* __restrict__ hinbase,  // upstream h (4 slots), null for L0
    unsigned short* __restrict__ hbase,          // own h (4 slots)
    float* __restrict__ c,                       // [1024][64] fp32 transposed
    const unsigned short* __restrict__ Wih,      // null for L0
    const unsigned short* __restrict__ Whh,
    const float* __restrict__ bias,
    const float* __restrict__ strokes,           // L0 only
    const float* __restrict__ Wih0,              // L0 only, fp32 [4096][3]
    float* gbuf, int* fOwn, const int* fProd, const int* fCons) {
  constexpr int NK = L0L ? 8 : 16;
  const int lane = tid & 63;
  const int w = tid >> 6;
  const int nl = lane & 15;
  const int kq8 = (lane >> 4) << 3;

  const unsigned short* Wm;
  int k0beg;
  bool useHin;
  if (L0L) { Wm = Whh; k0beg = w * 256; useHin = false; }
  else     { Wm = (w < 2) ? Wih : Whh; k0beg = (w & 1) * 512; useHin = (w < 2); }

  short8 bw[NK][4];
#pragma unroll
  for (int ns = 0; ns < 4; ++ns) {
    int jgl = wgl * 16 + ns * 4 + (nl >> 2);
    int row = (nl & 3) * HD + jgl;                 // gate-major weight row
    const unsigned short* wr = Wm + (size_t)row * HD + kq8 + k0beg;
#pragma unroll
    for (int k = 0; k < NK; ++k) bw[k][ns] = *(const short8*)(wr + k * 32);
  }

  const int myf = wgl * 4 + w;
  const int bb = (lane >> 4) << 2;
  float* gs = gbuf + w * 4096;

  for (int t = 0; t < TD; ++t) {
    // ---- RAW waits (all waves poll independently; ends with vmcnt==0) ----
    if (L0L) {
      if (t > 0) wait_ge(fOwn, lane, t);
    } else {
      if (t > 0) wait_ge2(fOwn, t, fProd, t + 1, lane);
      else       wait_ge(fProd, lane, 1);
    }
    // ---- WAR early probe (check-early/use-late; flags are monotonic) ----
    bool war_ok = true;
    if (t >= 4) { int4v v; fload4(v, fCons + lane * 4); war_ok = all_ge(v, t - 3); }

    const unsigned short* A = useHin ? (hinbase + (size_t)(t & 3) * BH)
                                     : (hbase + (size_t)((t - 1) & 3) * BH);
    const unsigned short* arow = A + nl * HD + kq8 + k0beg;

    f32x4 acc[4][4];
    const f32x4 z4 = {0.f, 0.f, 0.f, 0.f};
#pragma unroll
    for (int ns = 0; ns < 4; ++ns)
#pragma unroll
      for (int mt = 0; mt < 4; ++mt) acc[ns][mt] = z4;

    gemm_bw<NK>(arow, bw, acc);

#pragma unroll
    for (int ns = 0; ns < 4; ++ns) {
      int gn = ns * 16 + nl;
#pragma unroll
      for (int mt = 0; mt < 4; ++mt)
#pragma unroll
        for (int r = 0; r < 4; ++r)
          gs[sw(gn, mt * 16 + bb + r)] = acc[ns][mt][r];
    }
    __syncthreads();

    // rare path: consumer of the slot we're about to overwrite still reading
    if (!war_ok) wait_ge(fCons, lane, t - 3);

    unsigned short* hout = hbase + (size_t)(t & 3) * BH;
#pragma unroll
    for (int it = 0; it < 2; ++it) {
      int item = it * 256 + tid;
      int jp = item >> 6;          // 0..7 pair of j
      int b = item & 63;
      unsigned hv[2];
#pragma unroll
      for (int u2 = 0; u2 < 2; ++u2) {
        int jj = jp * 2 + u2;
        int j = wgl * 16 + jj;
        float p[4];
#pragma unroll
        for (int g = 0; g < 4; ++g) {
          int a = sw(jj * 4 + g, b);
          p[g] = gbuf[a] + gbuf[4096 + a] + gbuf[8192 + a] + gbuf[12288 + a] + bias[g * HD + j];
        }
        if (L0L) {
          const float* xr = strokes + ((size_t)b * TD + t) * 3;
          float x0 = xr[0], x1 = xr[1], x2 = xr[2];
#pragma unroll
          for (int g = 0; g < 4; ++g) {
            const float* wr = Wih0 + (size_t)(g * HD + j) * 3;
            p[g] += x0 * wr[0] + x1 * wr[1] + x2 * wr[2];
          }
        }
        float iv = sigmoidf_(p[0]);
        float fv = sigmoidf_(p[1]);
        float gv = tanhf(p[2]);
        float ov = sigmoidf_(p[3]);
        int ci = j * BD + b;       // CU-private, normal cached RMW
        float cn = fv * c[ci] + iv * gv;
        c[ci] = cn;
        hv[u2] = (unsigned)f2bf(ov * tanhf(cn));
      }
      unsigned packed = hv[0] | (hv[1] << 16);
      __hip_atomic_store((unsigned*)(hout + (size_t)b * HD + wgl * 16 + jp * 2), packed,
                         __ATOMIC_RELAXED, __HIP_MEMORY_SCOPE_AGENT);
    }
    // drain own h stores to agent scope, then publish per-wave progress flag
    asm volatile("s_waitcnt vmcnt(0)" ::: "memory");
    if (lane == 0)
      __hip_atomic_store(fOwn + myf, t + 1, __ATOMIC_RELAXED, __HIP_MEMORY_SCOPE_AGENT);
    __syncthreads();  // gbuf WAR for next iteration
  }
}

// ---------------- output projection driver (2 WGs x 64 o-columns) ----------------
__device__ __forceinline__ void run_out(
    int wgo, int tid,
    const unsigned short* __restrict__ h2base,
    const unsigned short* __restrict__ Wo,   // bf16 [128][1024] padded
    const float* __restrict__ bo,
    float* __restrict__ outp, float* gbuf, int* fOwn, const int* fProd) {
  const int lane = tid & 63;
  const int w = tid >> 6;
  const int nl = lane & 15;
  const int kq8 = (lane >> 4) << 3;
  const int k0beg = w * 256;

  short8 bw[8][4];
#pragma unroll
  for (int ns = 0; ns < 4; ++ns) {
    int o = wgo * 64 + ns * 16 + nl;
    const unsigned short* wr = Wo + (size_t)o * HD + kq8 + k0beg;
#pragma unroll
    for (int k = 0; k < 8; ++k) bw[k][ns] = *(const short8*)(wr + k * 32);
  }

  const int myf = wgo * 4 + w;
  const int bb = (lane >> 4) << 2;
  float* gs = gbuf + w * 4096;

  for (int t = 0; t < TD; ++t) {
    wait_ge(fProd, lane, t + 1);   // h2[t] published

    const unsigned short* arow = h2base + (size_t)(t & 3) * BH + nl * HD + kq8 + k0beg;

    f32x4 acc[4][4];
    const f32x4 z4 = {0.f, 0.f, 0.f, 0.f};
#pragma unroll
    for (int ns = 0; ns < 4; ++ns)
#pragma unroll
      for (int mt = 0; mt < 4; ++mt) acc[ns][mt] = z4;

    gemm_bw<8>(arow, bw, acc);

#pragma unroll
    for (int ns = 0; ns < 4; ++ns) {
      int gn = ns * 16 + nl;
#pragma unroll
      for (int mt = 0; mt < 4; ++mt)
#pragma unroll
        for (int r = 0; r < 4; ++r)
          gs[sw(gn, mt * 16 + bb + r)] = acc[ns][mt][r];
    }
    __syncthreads();

#pragma unroll
    for (int it = 0; it < 16; ++it) {
      int item = it * 256 + tid;
      int ol = item >> 6;
      int b = item & 63;
      int o = wgo * 64 + ol;
      int a = sw(ol, b);
      float v = gbuf[a] + gbuf[4096 + a] + gbuf[8192 + a] + gbuf[12288 + a] + bo[o];
      if (o < 121) outp[((size_t)b * TD + t) * 121 + o] = v;
    }
    // A-reads of h2[t] fully retired (gemm_bw drains to vmcnt 0) -> signal
    // L2's WAR consumers. outp stores may still be in flight (irrelevant).
    if (lane == 0)
      __hip_atomic_store(fOwn + myf, t + 1, __ATOMIC_RELAXED, __HIP_MEMORY_SCOPE_AGENT);
    __syncthreads();  // gbuf WAR
  }
}

// ---------------- main kernel ----------------
// WGs 0..63 layer0, 64..127 layer1, 128..191 layer2, 192..193 out-proj.
// Plain launch; 194 blocks <= 256 CUs, co-resident (dataflow waits require it,
// same co-residency contract as the previous global-barrier version).
__global__ void __launch_bounds__(256, 1)
lstm_main(const float* __restrict__ strokes, const float* __restrict__ Wih0,
          float* __restrict__ outp, void* __restrict__ wsv) {
  __shared__ float gbuf[16384];  // 64 KB: 4 K-slices x [64 gn][64 b]
  unsigned short* u = (unsigned short*)wsv;
  float* fr = (float*)((char*)wsv + FBYTE_BASE);
  int* flags = (int*)fr + FOFF_FLAGS;
  int* f0 = flags;
  int* f1 = flags + 256;
  int* f2 = flags + 512;
  int* f3 = flags + 768;

  const int wg = blockIdx.x;
  const int tid = threadIdx.x;

  if (wg < 64) {
    run_layer<true>(wg, tid, nullptr, u + OFF_H0, fr + FOFF_C0,
                    nullptr, u + OFF_WHH0, fr + FOFF_B0, strokes, Wih0, gbuf,
                    f0, nullptr, f1);
  } else if (wg < 128) {
    run_layer<false>(wg - 64, tid, u + OFF_H0, u + OFF_H1, fr + FOFF_C1,
                     u + OFF_WIH1, u + OFF_WHH1, fr + FOFF_B1, nullptr, nullptr, gbuf,
                     f1, f0, f2);
  } else if (wg < 192) {
    run_layer<false>(wg - 128, tid, u + OFF_H1, u + OFF_H2, fr + FOFF_C2,
                     u + OFF_WIH2, u + OFF_WHH2, fr + FOFF_B2, nullptr, nullptr, gbuf,
                     f2, f1, f3);
  } else {
    run_out(wg - 192, tid, u + OFF_H2, u + OFF_WOUT, fr + FOFF_BOUT, outp, gbuf,
            f3, f2);
  }
}

extern "C" void kernel_launch(void* const* d_in, const int* in_sizes, int n_in,
                              void* d_out, int out_size, void* d_ws, size_t ws_size,
                              hipStream_t stream) {
  const float* strokes = (const float*)d_in[0];
  const float* Wih0 = (const float*)d_in[1];
  const float* Whh0 = (const float*)d_in[2];
  const float* bih0 = (const float*)d_in[3];
  const float* bhh0 = (const float*)d_in[4];
  const float* Wih1 = (const float*)d_in[5];
  const float* Whh1 = (const float*)d_in[6];
  const float* bih1 = (const float*)d_in[7];
  const float* bhh1 = (const float*)d_in[8];
  const float* Wih2 = (const float*)d_in[9];
  const float* Whh2 = (const float*)d_in[10];
  const float* bih2 = (const float*)d_in[11];
  const float* bhh2 = (const float*)d_in[12];
  const float* Wout = (const float*)d_in[13];
  const float* bout = (const float*)d_in[14];
  float* outp = (float*)d_out;

  hipLaunchKernelGGL(prep_kernel, dim3(4096), dim3(256), 0, stream,
                     Whh0, Wih1, Whh1, Wih2, Whh2, Wout,
                     bih0, bhh0, bih1, bhh1, bih2, bhh2, bout, d_ws);

  hipLaunchKernelGGL(lstm_main, dim3(NBLK), dim3(256), 0, stream,
                     strokes, Wih0, outp, d_ws);
}